// Round 14
// baseline (213.017 us; speedup 1.0000x reference)
//
#include <hip/hip_runtime.h>
#include <math.h>
#include <stdint.h>

// ---- static problem sizes ----
#define S_    32        // sentences
#define BV_   16        // videos
#define M_    128       // moments
#define C_    256       // channels
#define NN    4096      // N*N
#define P_    2080      // triu(64) count
#define BP    33280     // BV_*P_
#define NSAMP 512       // neg samples per sentence
#define CAP   8192      // candidate buffer capacity (select v5)

// ---------------- Threefry-2x32 (exact JAX replication, key=(0,42)) -------------
__device__ __forceinline__ uint32_t rotl32(uint32_t x, int n){ return (x<<n) | (x>>(32-n)); }

__device__ __forceinline__ void threefry2x32(uint32_t k0, uint32_t k1, uint32_t &x0, uint32_t &x1){
  uint32_t ks2 = k0 ^ k1 ^ 0x1BD11BDAu;
  x0 += k0; x1 += k1;
  #define TF_R(r) { x0 += x1; x1 = rotl32(x1, r); x1 ^= x0; }
  TF_R(13) TF_R(15) TF_R(26) TF_R(6)
  x0 += k1;  x1 += ks2 + 1u;
  TF_R(17) TF_R(29) TF_R(16) TF_R(24)
  x0 += ks2; x1 += k0 + 2u;
  TF_R(13) TF_R(15) TF_R(26) TF_R(6)
  x0 += k0;  x1 += k1 + 3u;
  TF_R(17) TF_R(29) TF_R(16) TF_R(24)
  x0 += k1;  x1 += ks2 + 4u;
  TF_R(13) TF_R(15) TF_R(26) TF_R(6)
  x0 += ks2; x1 += k0 + 5u;
  #undef TF_R
}

// p in [0,2080) -> triangle (i,j), exact
__device__ __forceinline__ void p_to_ij(int p, int &i, int &j){
  i = (int)((129.0f - sqrtf((float)(16641 - 8*p))) * 0.5f);
  while(64*(i+1) - ((i+1)*i)/2 <= p) ++i;
  while(64*i - (i*(i-1))/2 > p) --i;
  j = i + (p - (64*i - (i*(i-1))/2));
}

// ============== kernel 1: top-2 per moment (R6-proven, 128 blocks) ================
__global__ __launch_bounds__(256) void k_topk(const float* __restrict__ iou2ds,
                                              int* __restrict__ fpk){
  int m = blockIdx.x;
  const float* row = iou2ds + (size_t)m*NN;
  float v1=-1e30f, v2=-1e30f; int i1=0x7FFFFFFF, i2=0x7FFFFFFF;
  for(int f=threadIdx.x; f<NN; f+=256){
    int ti = f>>6, tj = f&63;
    if(tj < ti) continue;
    float v = row[f];
    if(v > v1 || (v == v1 && f < i1)){ v2=v1; i2=i1; v1=v; i1=f; }
    else if(v > v2 || (v == v2 && f < i2)){ v2=v; i2=f; }
  }
  __shared__ float sv1[256], sv2[256];
  __shared__ int   si1[256], si2[256];
  sv1[threadIdx.x]=v1; sv2[threadIdx.x]=v2; si1[threadIdx.x]=i1; si2[threadIdx.x]=i2;
  for(int stp=128; stp>0; stp>>=1){
    __syncthreads();
    if((int)threadIdx.x < stp){
      float a1=sv1[threadIdx.x], a2=sv2[threadIdx.x];
      int   x1=si1[threadIdx.x], x2=si2[threadIdx.x];
      float b1=sv1[threadIdx.x+stp], b2=sv2[threadIdx.x+stp];
      int   y1=si1[threadIdx.x+stp], y2=si2[threadIdx.x+stp];
      float m1v, m2v; int m1i, m2i;
      bool aTop = (a1 > b1) || (a1 == b1 && x1 < y1);
      if(aTop){
        m1v=a1; m1i=x1;
        if((a2 > b1) || (a2 == b1 && x2 < y1)){ m2v=a2; m2i=x2; } else { m2v=b1; m2i=y1; }
      } else {
        m1v=b1; m1i=y1;
        if((b2 > a1) || (b2 == a1 && y2 < x1)){ m2v=b2; m2i=y2; } else { m2v=a1; m2i=x1; }
      }
      sv1[threadIdx.x]=m1v; sv2[threadIdx.x]=m2v; si1[threadIdx.x]=m1i; si2[threadIdx.x]=m2i;
    }
  }
  __syncthreads();
  if(threadIdx.x==0){
    fpk[m*2+0] = si1[0];
    fpk[m*2+1] = si2[0];
  }
}

// ============== kernel 2: pos_vf (normalized) + qsumT (R6-proven) =================
__global__ __launch_bounds__(256) void k_pos(const float* __restrict__ vfeat,
                                             const int* __restrict__ fpk,
                                             float* __restrict__ pos_vf,
                                             float* __restrict__ qsumT){
  int s = blockIdx.x;            // 32
  int c = threadIdx.x;           // 256
  __shared__ float wsum[4];
  __shared__ float s_inv;
  float qs = 0.f;
  for(int r=0; r<8; ++r){
    int row = s*8 + r;
    int fp = fpk[row];
    float v = vfeat[((size_t)s*C_ + c)*NN + fp];
    float ss = v*v;
    for(int o=32;o>0;o>>=1) ss += __shfl_down(ss, o, 64);
    if((c&63)==0) wsum[c>>6]=ss;
    __syncthreads();
    if(c==0){
      float tot = wsum[0]+wsum[1]+wsum[2]+wsum[3];
      s_inv = 1.0f / fmaxf(sqrtf(tot), 1e-12f);
    }
    __syncthreads();
    float pv = v * s_inv;
    pos_vf[(size_t)row*C_ + c] = pv;
    qs += pv;
  }
  qsumT[c*32 + s] = qs;
}

// ============== kernel 3: norm + bank fill, float4 staging (R13-proven) ===========
// dyn LDS layout: tile[256*65] | ssp4[1024] | invs[64]  => 17728 floats = 70912 B
__global__ __launch_bounds__(256) void k_bank(const float* __restrict__ vfeat,
                                              float* __restrict__ bank){
  extern __shared__ char dyn_sm[];
  float* tile = (float*)dyn_sm;                    // [256][65]
  float* ssp4 = (float*)dyn_sm + 256*65;           // [256][4]
  float* invs = (float*)dyn_sm + 256*65 + 1024;    // [64]

  const int i = blockIdx.x;      // triangle row
  const int b = blockIdx.y;      // video
  const int t = threadIdx.x;
  const float* basep = vfeat + (size_t)(2*b)*C_*NN + (size_t)i*64;
  const int cc0 = t >> 4;        // 0..15
  const int j0  = (t & 15) * 4;  // 0..60 step 4

  float sq0=0.f, sq1=0.f, sq2=0.f, sq3=0.f;
  #pragma unroll
  for(int it=0; it<16; ++it){
    int cc = it*16 + cc0;
    float4 v = *(const float4*)(basep + (size_t)cc*NN + j0);  // 16B/lane coalesced
    tile[cc*65 + j0+0] = v.x; tile[cc*65 + j0+1] = v.y;
    tile[cc*65 + j0+2] = v.z; tile[cc*65 + j0+3] = v.w;
    sq0 += v.x*v.x; sq1 += v.y*v.y; sq2 += v.z*v.z; sq3 += v.w*v.w;
  }
  ssp4[t*4+0]=sq0; ssp4[t*4+1]=sq1; ssp4[t*4+2]=sq2; ssp4[t*4+3]=sq3;
  __syncthreads();
  if(t < 64){
    float tot = 0.f;
    #pragma unroll
    for(int g=0; g<16; ++g) tot += ssp4[g*64 + t];   // conflict-free, fixed order
    invs[t] = 1.0f/fmaxf(sqrtf(tot), 1e-12f);
  }
  __syncthreads();

  const int start = 64*i - (i*(i-1))/2;
  for(int jj=i; jj<64; ++jj){
    size_t row = (size_t)b*P_ + start + (jj - i);
    bank[row*C_ + t] = tile[t*65 + jj] * invs[jj];
  }
}

// ============== kernel 4: fused GEMM + keys (R6-proven) ===========================
__global__ __launch_bounds__(256) void k_fused_keys(const float* __restrict__ bank,
                                                    const float* __restrict__ qsumT,
                                                    const float* __restrict__ iou2d,
                                                    unsigned int* __restrict__ ukey){
  __shared__ float tile[32*257];       // [cc][j]
  const int t = threadIdx.x;
  const int j = blockIdx.x*256 + t;    // 130*256 = 33280 exactly

  int bv = j / P_;
  int p  = j - bv*P_;
  int pi, pj; p_to_ij(p, pi, pj);
  int fp = pi*64 + pj;
  float iou0 = iou2d[(size_t)(2*bv)*NN + fp];
  float iou1 = iou2d[(size_t)(2*bv+1)*NN + fp];

  float acc[32];
  #pragma unroll
  for(int s=0;s<32;s++) acc[s]=0.f;

  for(int cb=0; cb<8; ++cb){
    __syncthreads();
    #pragma unroll
    for(int it=0; it<8; ++it){
      int idx = it*256 + t;            // 0..2047 float4 units
      int jj  = idx >> 3;              // 0..255
      int c4  = idx & 7;               // 0..7
      float4 v = ((const float4*)bank)[ (size_t)(blockIdx.x*256 + jj)*64 + cb*8 + c4 ];
      tile[(c4*4+0)*257 + jj]=v.x; tile[(c4*4+1)*257 + jj]=v.y;
      tile[(c4*4+2)*257 + jj]=v.z; tile[(c4*4+3)*257 + jj]=v.w;
    }
    __syncthreads();
    const float* qb = qsumT + cb*32*32;
    #pragma unroll 2
    for(int cc=0; cc<32; ++cc){
      float v = tile[cc*257 + t];
      const float* qc = qb + cc*32;    // uniform -> scalar loads
      #pragma unroll
      for(int s=0;s<32;s++) acc[s] = fmaf(qc[s], v, acc[s]);
    }
  }

  #pragma unroll 1
  for(int s=0;s<32;s++){
    float fz = 0.0625f*acc[s] + 0.5f;
    bool pos = ((s>>1)==bv) && (((s&1)?iou1:iou0) > 0.5f);
    float val = pos ? 0.f : fz*fz;
    float key;
    if(val > 0.f){
      float logw = logf(fmaxf(val, 1e-30f));
      unsigned int f = (unsigned int)(s*BP + j);
      const unsigned int HALF = 532480u;   // (S_*BP)/2
      bool second = f >= HALF;
      uint32_t x0 = second ? (f - HALF) : f;
      uint32_t x1 = second ? f : (f + HALF);
      threefry2x32(0u, 42u, x0, x1);
      uint32_t bits = second ? x1 : x0;
      uint32_t fb = (bits >> 9) | 0x3f800000u;
      float f01 = __uint_as_float(fb) - 1.0f;
      const float mn = 1e-7f, mx = 1.0f - 1e-7f;
      float u = fmaxf(mn, f01*(mx-mn) + mn);
      float g = -logf(-logf(u));
      key = logw + g;
    } else {
      key = -INFINITY;
    }
    unsigned int kb = __float_as_uint(key);
    kb = (kb & 0x80000000u) ? ~kb : (kb | 0x80000000u);
    ukey[(size_t)s*BP + j] = kb;
  }
}

// ============== kernel 5: exact top-512 v5 — candidate compaction =================
// Pass 1: level-0 hist (global). Pass 2: classify — top-byte>B* emit directly
// (provably > ustar), top-byte==B* compact to LDS cand buffer. Levels 1-3 + emit
// run over candidates only. Final rank-sort by index makes output deterministic
// regardless of atomic emission order. Full-row fallback for cand overflow.
__global__ __launch_bounds__(1024) void k_select(const unsigned int* __restrict__ ukey,
                                                 int* __restrict__ neglist){
  extern __shared__ char dyn_sm[];
  unsigned int* cand_key = (unsigned int*)dyn_sm;             // [CAP]
  int*          cand_idx = (int*)dyn_sm + CAP;                // [CAP]
  unsigned int* hist     = (unsigned int*)dyn_sm + 2*CAP;     // [256*17]
  int*          list_lds = (int*)dyn_sm + 2*CAP + 256*17;     // [512]
  __shared__ int s_wv[16];
  __shared__ unsigned int s_prefix;
  __shared__ int s_cntgt, s_need, s_gt, s_nc;

  const int s = blockIdx.x;
  const int t = threadIdx.x;
  const int lane = t & 63;
  const int col  = t & 15;
  const unsigned int* grow = ukey + (size_t)s*BP;

  // ---- pass 1: level-0 histogram ----
  for(int k=t; k<256*17; k+=1024) hist[k] = 0;
  if(t==0){ s_gt = 0; s_nc = 0; }
  __syncthreads();
  for(int k=t; k<BP; k+=1024)
    atomicAdd(&hist[(grow[k] >> 24)*17 + col], 1u);
  __syncthreads();
  {
    int v = 0; unsigned int h = 0;
    if(t < 256){
      const unsigned int* hr = hist + t*17;
      #pragma unroll
      for(int c=0;c<16;c++) h += hr[c];
      v = (int)h;
      #pragma unroll
      for(int off=1; off<64; off<<=1){
        int src = lane + off;
        int o = __shfl(v, (src<64)?src:lane, 64);
        v += (src<64)? o : 0;
      }
      if(lane==0) s_wv[t>>6] = v;
    }
    __syncthreads();
    if(t < 256){
      int wv4 = t>>6, tail = 0;
      for(int w2=wv4+1; w2<4; ++w2) tail += s_wv[w2];
      int Sb  = v + tail;
      int Sb1 = Sb - (int)h;
      if(Sb >= NSAMP && Sb1 < NSAMP){
        s_prefix = ((unsigned int)t) << 24;
        s_cntgt  = Sb1;
        s_need   = NSAMP - Sb1;
      }
    }
    __syncthreads();
  }
  unsigned int prefix = s_prefix;
  int cnt_gt = s_cntgt, need = s_need;
  const unsigned int Bstar = prefix >> 24;
  unsigned int pmask = 0xFF000000u;
  __syncthreads();

  // ---- pass 2: classify (emit definite-gt; compact boundary bin) ----
  for(int k=t; k<BP; k+=1024){
    unsigned int u = grow[k];
    unsigned int top = u >> 24;
    if(top > Bstar){
      int sl = atomicAdd(&s_gt, 1);
      list_lds[sl] = k;
    } else if(top == Bstar){
      int c = atomicAdd(&s_nc, 1);
      if(c < CAP){ cand_key[c] = u; cand_idx[c] = k; }
    }
  }
  __syncthreads();
  const int nc = s_nc;

  if(nc <= CAP){
    // ---- levels 1-3 over candidates only ----
    for(int lev=1; lev<4; ++lev){
      const int shift = 24 - 8*lev;
      for(int k=t; k<256*17; k+=1024) hist[k] = 0;
      __syncthreads();
      for(int c=t; c<nc; c+=1024){
        unsigned int u = cand_key[c];
        if((u & pmask) == prefix)
          atomicAdd(&hist[((u >> shift) & 255u)*17 + col], 1u);
      }
      __syncthreads();
      int v = 0; unsigned int h = 0;
      if(t < 256){
        const unsigned int* hr = hist + t*17;
        #pragma unroll
        for(int c=0;c<16;c++) h += hr[c];
        v = (int)h;
        #pragma unroll
        for(int off=1; off<64; off<<=1){
          int src = lane + off;
          int o = __shfl(v, (src<64)?src:lane, 64);
          v += (src<64)? o : 0;
        }
        if(lane==0) s_wv[t>>6] = v;
      }
      __syncthreads();
      if(t < 256){
        int wv4 = t>>6, tail = 0;
        for(int w2=wv4+1; w2<4; ++w2) tail += s_wv[w2];
        int Sb  = v + tail;
        int Sb1 = Sb - (int)h;
        if(Sb >= need && Sb1 < need){
          s_prefix = prefix | (((unsigned int)t) << shift);
          s_cntgt  = cnt_gt + Sb1;
          s_need   = need - Sb1;
        }
      }
      __syncthreads();
      prefix = s_prefix; cnt_gt = s_cntgt; need = s_need;
      pmask |= (0xFFu << shift);
      __syncthreads();
    }
    const unsigned int ustar = prefix;
    const int quota = need;

    for(int c=t; c<nc; c+=1024){
      if(cand_key[c] > ustar){
        int sl = atomicAdd(&s_gt, 1);
        list_lds[sl] = cand_idx[c];
      }
    }
    __syncthreads();
    for(int c=t; c<nc; c+=1024){
      if(cand_key[c] == ustar){
        int my = cand_idx[c];
        int r = 0;
        for(int j2=0; j2<nc; ++j2) r += (cand_key[j2]==ustar && cand_idx[j2] < my);
        if(r < quota) list_lds[cnt_gt + r] = my;
      }
    }
    __syncthreads();
  } else {
    // ---- fallback: full-row global radix levels 1-3 (rare; adversarial data) ----
    for(int lev=1; lev<4; ++lev){
      const int shift = 24 - 8*lev;
      for(int k=t; k<256*17; k+=1024) hist[k] = 0;
      __syncthreads();
      for(int k=t; k<BP; k+=1024){
        unsigned int u = grow[k];
        if((u & pmask) == prefix)
          atomicAdd(&hist[((u >> shift) & 255u)*17 + col], 1u);
      }
      __syncthreads();
      int v = 0; unsigned int h = 0;
      if(t < 256){
        const unsigned int* hr = hist + t*17;
        #pragma unroll
        for(int c=0;c<16;c++) h += hr[c];
        v = (int)h;
        #pragma unroll
        for(int off=1; off<64; off<<=1){
          int src = lane + off;
          int o = __shfl(v, (src<64)?src:lane, 64);
          v += (src<64)? o : 0;
        }
        if(lane==0) s_wv[t>>6] = v;
      }
      __syncthreads();
      if(t < 256){
        int wv4 = t>>6, tail = 0;
        for(int w2=wv4+1; w2<4; ++w2) tail += s_wv[w2];
        int Sb  = v + tail;
        int Sb1 = Sb - (int)h;
        if(Sb >= need && Sb1 < need){
          s_prefix = prefix | (((unsigned int)t) << shift);
          s_cntgt  = cnt_gt + Sb1;
          s_need   = need - Sb1;
        }
      }
      __syncthreads();
      prefix = s_prefix; cnt_gt = s_cntgt; need = s_need;
      pmask |= (0xFFu << shift);
      __syncthreads();
    }
    const unsigned int ustar = prefix;
    const int quota = need;

    for(int k=t; k<BP; k+=1024){
      unsigned int u = grow[k];
      if((u >> 24) == Bstar && u > ustar){
        int sl = atomicAdd(&s_gt, 1);
        list_lds[sl] = k;
      }
    }
    __syncthreads();
    if(t==0){                          // serial eq (deterministic, degenerate only)
      int taken = 0;
      for(int k=0; k<BP && taken<quota; ++k)
        if(grow[k]==ustar){ list_lds[cnt_gt + taken] = k; ++taken; }
    }
    __syncthreads();
  }

  // ---- deterministic final ordering: rank-sort by index ----
  if(t < NSAMP){
    int my = list_lds[t];
    int r = 0;
    for(int j2=0; j2<NSAMP; ++j2) r += (list_lds[j2] < my);
    neglist[s*NSAMP + r] = my;
  }
}

// ============== kernel 6: neg_sum per sentence (R6-proven, pv in LDS) =============
__global__ __launch_bounds__(512) void k_negsum(const float* __restrict__ bank,
                                                const float* __restrict__ pos_vf,
                                                const int* __restrict__ neglist,
                                                float* __restrict__ ns){
  int s = blockIdx.x;
  int t = threadIdx.x;           // 512
  __shared__ float pv[8][C_];
  for(int idx=t; idx<8*C_; idx+=512) pv[idx>>8][idx&255] = pos_vf[(size_t)(s*8)*C_ + idx];
  __syncthreads();
  int j = neglist[s*NSAMP + t];
  const float4* bp = (const float4*)(bank + (size_t)j*C_);
  float acc[8] = {0,0,0,0,0,0,0,0};
  for(int c4=0; c4<64; ++c4){
    float4 bv = bp[c4];
    #pragma unroll
    for(int a=0;a<8;a++){
      const float* pva = &pv[a][c4*4];
      acc[a] += bv.x*pva[0] + bv.y*pva[1] + bv.z*pva[2] + bv.w*pva[3];
    }
  }
  float e[8];
  #pragma unroll
  for(int a=0;a<8;a++){
    float v = expf(acc[a]/0.1f);
    for(int o=32;o>0;o>>=1) v += __shfl_down(v, o, 64);
    e[a] = v;
  }
  __shared__ float red[8][8];    // [wave][a]
  int wv = t>>6;
  if((t&63)==0){
    #pragma unroll
    for(int a=0;a<8;a++) red[wv][a]=e[a];
  }
  __syncthreads();
  if(t < 8){
    float tot = 0.f;
    for(int w=0; w<8; w++) tot += red[w][t];
    ns[s*8 + t] = tot;
  }
}

// ============== kernel 7: per-sentence loss partials (R6-proven) ==================
__global__ __launch_bounds__(64) void k_loss(const float* __restrict__ pos_vf,
                                             const float* __restrict__ ns,
                                             float* __restrict__ partial){
  int s = blockIdx.x;
  int t = threadIdx.x;           // 64 = 8 refs x 8 pos
  __shared__ float pv[8][260];
  for(int idx=t; idx<8*C_; idx+=64){
    pv[idx>>8][idx&255] = pos_vf[(size_t)(s*8)*C_ + idx];
  }
  __syncthreads();
  int a = t>>3, b = t&7;
  float dot = 0.f;
  for(int c=0;c<C_;c++) dot += pv[a][c]*pv[b][c];
  float pl = dot/0.1f;
  float term = logf(expf(pl) + ns[s*8+a]) - pl;
  for(int o=32;o>0;o>>=1) term += __shfl_down(term, o, 64);
  if(t==0) partial[s]=term;
}

// ============== kernel 8: final reduce (R6-proven) ================================
__global__ void k_final(const float* __restrict__ partial, float* __restrict__ out){
  int t = threadIdx.x;           // 64
  float v = (t < 32) ? partial[t] : 0.f;
  for(int o=32;o>0;o>>=1) v += __shfl_down(v, o, 64);
  if(t==0){
    float loss = v / 2048.0f;
    out[0] = loss * 1.0f;        // WEIGHT = 1.0
    out[1] = loss;
  }
}

// ======================= host launcher =============================================
extern "C" void kernel_launch(void* const* d_in, const int* in_sizes, int n_in,
                              void* d_out, int out_size, void* d_ws, size_t ws_size,
                              hipStream_t stream) {
  const float* video_feats = (const float*)d_in[0];
  const float* iou2d  = (const float*)d_in[4];
  const float* iou2ds = (const float*)d_in[5];

  // workspace layout (bytes, 256-aligned)
  const size_t o_fpk   = 0;            // 256 i32 (1024)
  const size_t o_pvf   = 1024;         // 256*256 f32 (262144)
  const size_t o_qsT   = 263168;       // 256*32 f32 (32768)
  const size_t o_bank  = 295936;       // 33280*256 f32 (34078720)
  const size_t o_ukey  = 34374656;     // 32*33280 u32 (4259840)
  const size_t o_list  = 38634496;     // 32*512 i32 (65536)
  const size_t o_ns    = 38700032;     // 256 f32 (1024)
  const size_t o_part  = 38701056;     // 32 f32 (128)
  const size_t NEED    = 38701312;
  if (ws_size < NEED) return;

  char* w = (char*)d_ws;
  int*          fpk     = (int*)(w + o_fpk);
  float*        pos_vf  = (float*)(w + o_pvf);
  float*        qsumT   = (float*)(w + o_qsT);
  float*        bank    = (float*)(w + o_bank);
  unsigned int* ukey    = (unsigned int*)(w + o_ukey);
  int*          neglist = (int*)(w + o_list);
  float*        ns      = (float*)(w + o_ns);
  float*        part    = (float*)(w + o_part);
  float*        out     = (float*)d_out;

  const int BK_LDS  = (256*65 + 1024 + 64) * 4;         // 70912 B
  const int SEL_LDS = (2*CAP + 256*17 + NSAMP) * 4;     // 84992 B
  static bool attr_set = false;
  if(!attr_set){
    (void)hipFuncSetAttribute((const void*)k_bank,
                              hipFuncAttributeMaxDynamicSharedMemorySize, BK_LDS);
    (void)hipFuncSetAttribute((const void*)k_select,
                              hipFuncAttributeMaxDynamicSharedMemorySize, SEL_LDS);
    attr_set = true;
  }

  k_topk<<<128, 256, 0, stream>>>(iou2ds, fpk);
  k_pos<<<32, 256, 0, stream>>>(video_feats, fpk, pos_vf, qsumT);
  k_bank<<<dim3(64,16), 256, BK_LDS, stream>>>(video_feats, bank);
  k_fused_keys<<<130, 256, 0, stream>>>(bank, qsumT, iou2d, ukey);
  k_select<<<32, 1024, SEL_LDS, stream>>>(ukey, neglist);
  k_negsum<<<32, 512, 0, stream>>>(bank, pos_vf, neglist, ns);
  k_loss<<<32, 64, 0, stream>>>(pos_vf, ns, part);
  k_final<<<1, 64, 0, stream>>>(part, out);
}